// Round 11
// baseline (649.983 us; speedup 1.0000x reference)
//
#include <hip/hip_runtime.h>
#include <hip/hip_bf16.h>

#define T_TOK 8192
#define DMODEL 1024
#define DFF 2048
#define NEXP 8

typedef __attribute__((ext_vector_type(8))) short short8v;
typedef __attribute__((ext_vector_type(4))) float floatx4;
typedef __attribute__((ext_vector_type(4))) ushort ushort4v;

__device__ __forceinline__ ushort f2bf(float f) {
  union { float f; unsigned u; } v; v.f = f;
  unsigned u = v.u;
  unsigned r = (u + 0x7FFFu + ((u >> 16) & 1u)) >> 16;
  return (ushort)r;
}
__device__ __forceinline__ float bf2f(ushort b) {
  union { unsigned u; float f; } v; v.u = ((unsigned)b) << 16;
  return v.f;
}
__device__ __forceinline__ void gload16(const void* g, void* l) {
  __builtin_amdgcn_global_load_lds(
      (const __attribute__((address_space(1))) unsigned int*)g,
      (__attribute__((address_space(3))) unsigned int*)l, 16, 0, 0);
}
__device__ __forceinline__ short8v dsr128(unsigned off) {
  short8v r;
  asm volatile("ds_read_b128 %0, %1" : "=v"(r) : "v"(off));
  return r;
}
#define VMW(n) asm volatile("s_waitcnt vmcnt(" #n ")" ::: "memory")
#define LG0()  asm volatile("s_waitcnt lgkmcnt(0)" ::: "memory")
#define BAR()  asm volatile("s_barrier" ::: "memory")
#define SB0()  __builtin_amdgcn_sched_barrier(0)

// ---------------- gating: 8 tokens/block, conflict-free Wg LDS, fused x->bf16 ----------------
// norm-modulation in the reference is a per-token uniform shift across experts:
// invariant for top-k indices and softmax(topv) -> skipped entirely.
// Wg LDS layout: addr(d,e) = 8d + e + (d>>2) (monotone pad -> injective).
__global__ __launch_bounds__(256) void gating_kernel(
    const float* __restrict__ x, const float* __restrict__ Wg,
    const float* __restrict__ bg, int* __restrict__ meta,
    int* __restrict__ te, float* __restrict__ tg, float* __restrict__ entWs,
    ushort* __restrict__ xb) {
  __shared__ float wgT[8448];
  __shared__ float sbg[NEXP];
  __shared__ int cnt_s[NEXP];
  __shared__ float ent_s;
  int tid = threadIdx.x;
#pragma unroll
  for (int k = 0; k < 8; ++k) {
    int g4 = tid + 256 * k;
    float4 v = ((const float4*)Wg)[g4];
    int q = g4 * 4;
    int f = q >> 5;
    wgT[q + f]     = v.x;
    wgT[q + 1 + f] = v.y;
    wgT[q + 2 + f] = v.z;
    wgT[q + 3 + f] = v.w;
  }
  if (tid < NEXP) { sbg[tid] = bg[tid]; cnt_s[tid] = 0; }
  if (tid == 0) ent_s = 0.f;
  __syncthreads();

  int wid = tid >> 6, lane = tid & 63;
#pragma unroll 1
  for (int it = 0; it < 2; ++it) {
    int t = blockIdx.x * 8 + wid * 2 + it;
    const float* xr = x + (long)t * DMODEL;
    ushort* xbr = xb + (long)t * DMODEL;
    float acc[NEXP];
#pragma unroll
    for (int e = 0; e < NEXP; ++e) acc[e] = 0.f;
#pragma unroll
    for (int i = 0; i < 4; ++i) {
      int dbase = i * 256 + lane * 4;
      int pad = i * 64 + lane;
      float4 xv = *(const float4*)(xr + dbase);
      ushort4v s;
      s[0] = f2bf(xv.x); s[1] = f2bf(xv.y); s[2] = f2bf(xv.z); s[3] = f2bf(xv.w);
      *(ushort4v*)(xbr + dbase) = s;
      float xj[4] = {xv.x, xv.y, xv.z, xv.w};
#pragma unroll
      for (int j = 0; j < 4; ++j) {
        int base = 8 * (dbase + j) + pad;
#pragma unroll
        for (int e = 0; e < NEXP; ++e) acc[e] += xj[j] * wgT[base + e];
      }
    }
#pragma unroll
    for (int off = 32; off; off >>= 1)
#pragma unroll
      for (int e = 0; e < NEXP; ++e) acc[e] += __shfl_xor(acc[e], off, 64);
    if (lane == 0) {
      float lg[NEXP];
#pragma unroll
      for (int e = 0; e < NEXP; ++e) lg[e] = acc[e] + sbg[e];
      int e1 = 0; float v1 = lg[0];
#pragma unroll
      for (int e = 1; e < NEXP; ++e) if (lg[e] > v1) { v1 = lg[e]; e1 = e; }
      int e2 = -1; float v2 = -1e30f;
#pragma unroll
      for (int e = 0; e < NEXP; ++e) if (e != e1 && lg[e] > v2) { v2 = lg[e]; e2 = e; }
      float p2 = expf(v2 - v1);
      float s = 1.f + p2;
      float g1 = 1.f / s, g2 = p2 / s;
      float ent = -(g1 * logf(fmaxf(g1, 1e-8f)) + g2 * logf(fmaxf(g2, 1e-8f)));
      atomicAdd(&cnt_s[e1], 1);
      atomicAdd(&cnt_s[e2], 1);
      atomicAdd(&ent_s, ent);
      te[2 * t] = e1; te[2 * t + 1] = e2;
      tg[2 * t] = g1; tg[2 * t + 1] = g2;
    }
  }
  __syncthreads();
  if (tid < NEXP && cnt_s[tid]) atomicAdd(&meta[tid], cnt_s[tid]);
  if (tid == 0) atomicAdd(entWs, ent_s * (1.f / T_TOK));
}

// meta layout (ints): counts @0..7, base @16..23, cursor @32..39
__global__ void prefix_kernel(int* __restrict__ meta) {
  if (threadIdx.x == 0) {
    int s = 0;
    for (int e = 0; e < NEXP; ++e) { meta[16 + e] = s; s += meta[e]; meta[32 + e] = 0; }
  }
}

__global__ void scatter_kernel(const int* __restrict__ te, const float* __restrict__ tg,
                               int* __restrict__ meta, int* __restrict__ tok,
                               float* __restrict__ gate, int* __restrict__ slotOf) {
  int t = blockIdx.x * blockDim.x + threadIdx.x;
  if (t >= T_TOK) return;
  for (int k = 0; k < 2; ++k) {
    int e = te[2 * t + k];
    int pos = atomicAdd(&meta[32 + e], 1);
    int slot = meta[16 + e] + pos;
    tok[slot] = t;
    gate[slot] = tg[2 * t + k];
    slotOf[2 * t + k] = slot;
  }
}

// ---------------- transpose+convert both weights; block 0 also does init ----------------
// Launched FIRST (stream order guarantees meta/entWs zeroed before gating runs).
// src[e][R][C] f32 -> dst[e][C][R] bf16.  id<4096: W1 (R=1024,C=2048); else W2.
__global__ __launch_bounds__(256) void tcvt2_kernel(
    const float* __restrict__ W1, const float* __restrict__ W2,
    ushort* __restrict__ w1t, ushort* __restrict__ w2t,
    int* __restrict__ meta, float* __restrict__ entWs) {
  int id = blockIdx.x;
  if (id == 0) {
    if (threadIdx.x < 64) meta[threadIdx.x] = 0;
    if (threadIdx.x == 64) *entWs = 0.f;
  }
  const float* src; ushort* dst; int R, C, r0, c0, e;
  if (id < 4096) {
    src = W1; dst = w1t; R = DMODEL; C = DFF;
    c0 = (id & 31) * 64; r0 = ((id >> 5) & 15) * 64; e = id >> 9;
  } else {
    int j = id - 4096;
    src = W2; dst = w2t; R = DFF; C = DMODEL;
    c0 = (j & 15) * 64; r0 = ((j >> 4) & 31) * 64; e = j >> 9;
  }
  __shared__ ushort tile[64][72];
  int tid = threadIdx.x;
  long eoff = (long)e * R * C;
  int lr = tid >> 4, lc = (tid & 15) * 4;
#pragma unroll
  for (int p = 0; p < 4; ++p) {
    int r = lr + p * 16;
    float4 v = *(const float4*)&src[eoff + (long)(r0 + r) * C + (c0 + lc)];
    tile[r][lc + 0] = f2bf(v.x); tile[r][lc + 1] = f2bf(v.y);
    tile[r][lc + 2] = f2bf(v.z); tile[r][lc + 3] = f2bf(v.w);
  }
  __syncthreads();
  int sr = tid >> 3, sc = (tid & 7) * 8;
#pragma unroll
  for (int p = 0; p < 2; ++p) {
    int c = sr + p * 32;
    short8v v;
#pragma unroll
    for (int j = 0; j < 8; ++j) v[j] = (short)tile[sc + j][c];
    *(short8v*)&dst[eoff + (long)(c0 + c) * R + (r0 + sc)] = v;
  }
}

// ================= GEMM1: round-7 LDS pipeline (proven best), verbatim =================
// Block tile 128(M)x256(N), BK=32; wave tile 128x64 (1Mx4N), acc[8][4].
// LDS: A [3][128][32] bf16 = 24 KB @0, B [3][256][32] = 48 KB @24576 -> 72 KB.
__device__ __forceinline__ void gemm_pipe(
    int NT, const char* aP0, const char* aP1,
    const char* bP0, const char* bP1, const char* bP2, const char* bP3,
    char* lds, int tid, floatx4 (&acc)[8][4]) {
  const unsigned ldsU = (unsigned)(unsigned long)lds;
  int lane = tid & 63, wid = tid >> 6;
  int lr = lane & 15, lg = lane >> 4;
  unsigned offA[8], offB[4];
#pragma unroll
  for (int mi = 0; mi < 8; ++mi) {
    int row = mi * 16 + lr;
    offA[mi] = row * 64 + ((lg * 16) ^ (((row >> 1) & 3) << 4));
  }
#pragma unroll
  for (int ni = 0; ni < 4; ++ni) {
    int row = wid * 64 + ni * 16 + lr;
    offB[ni] = row * 64 + ((lg * 16) ^ (((row >> 1) & 3) << 4));
  }

  auto STG_A = [&](int b, int t) {
    int koff = t * 64;
    char* d = lds + b * 8192;
    gload16(aP0 + koff, d + tid * 16);
    gload16(aP1 + koff, d + 4096 + tid * 16);
  };
  auto STG_B = [&](int b, int t) {
    int koff = t * 64;
    char* d = lds + 24576 + b * 16384;
    gload16(bP0 + koff, d + tid * 16);
    gload16(bP1 + koff, d + 4096 + tid * 16);
    gload16(bP2 + koff, d + 8192 + tid * 16);
    gload16(bP3 + koff, d + 12288 + tid * 16);
  };
  auto RDA = [&](int b, int mi) {
    return dsr128(ldsU + (unsigned)(b * 8192) + offA[mi]);
  };
  auto RDB = [&](int b, int ni) {
    return dsr128(ldsU + (unsigned)(24576 + b * 16384) + offB[ni]);
  };
  auto MM = [&](int mh, short8v* af, short8v* bf) {
#pragma unroll
    for (int mi = 0; mi < 4; ++mi)
#pragma unroll
      for (int ni = 0; ni < 4; ++ni)
        acc[mh * 4 + mi][ni] =
            __builtin_amdgcn_mfma_f32_16x16x32_bf16(af[mi], bf[ni], acc[mh * 4 + mi][ni], 0, 0, 0);
  };

  STG_A(0, 0); STG_B(0, 0);
  STG_A(1, 1); STG_B(1, 1);
  VMW(6); BAR();

  short8v af[4], bf[4];
  int b = 0;
  for (int t = 0; t + 2 < NT; ++t) {
    int bs = (b == 0) ? 2 : b - 1;
#pragma unroll
    for (int ni = 0; ni < 4; ++ni) bf[ni] = RDB(b, ni);
#pragma unroll
    for (int i = 0; i < 4; ++i) af[i] = RDA(b, i);
    STG_A(bs, t + 2);
    BAR(); LG0(); SB0();
    __builtin_amdgcn_s_setprio(1); MM(0, af, bf); __builtin_amdgcn_s_setprio(0);
    SB0(); BAR();
#pragma unroll
    for (int i = 0; i < 4; ++i) af[i] = RDA(b, 4 + i);
    STG_B(bs, t + 2);
    VMW(6);
    BAR(); LG0(); SB0();
    __builtin_amdgcn_s_setprio(1); MM(1, af, bf); __builtin_amdgcn_s_setprio(0);
    SB0(); BAR();
    b = (b == 2) ? 0 : b + 1;
  }
  {
#pragma unroll
    for (int ni = 0; ni < 4; ++ni) bf[ni] = RDB(b, ni);
#pragma unroll
    for (int i = 0; i < 4; ++i) af[i] = RDA(b, i);
    BAR(); LG0(); SB0();
    __builtin_amdgcn_s_setprio(1); MM(0, af, bf); __builtin_amdgcn_s_setprio(0);
    SB0(); BAR();
#pragma unroll
    for (int i = 0; i < 4; ++i) af[i] = RDA(b, 4 + i);
    VMW(0);
    BAR(); LG0(); SB0();
    __builtin_amdgcn_s_setprio(1); MM(1, af, bf); __builtin_amdgcn_s_setprio(0);
    SB0(); BAR();
    b = (b == 2) ? 0 : b + 1;
  }
  {
#pragma unroll
    for (int ni = 0; ni < 4; ++ni) bf[ni] = RDB(b, ni);
#pragma unroll
    for (int i = 0; i < 4; ++i) af[i] = RDA(b, i);
    BAR(); LG0(); SB0();
    __builtin_amdgcn_s_setprio(1); MM(0, af, bf); __builtin_amdgcn_s_setprio(0);
    SB0(); BAR();
#pragma unroll
    for (int i = 0; i < 4; ++i) af[i] = RDA(b, 4 + i);
    LG0(); SB0();
    __builtin_amdgcn_s_setprio(1); MM(1, af, bf); __builtin_amdgcn_s_setprio(0);
  }
}

__global__ __launch_bounds__(256, 2) void gemm1_kernel(
    const ushort* __restrict__ xb, const ushort* __restrict__ w1t,
    const float* __restrict__ b1, const int* __restrict__ meta,
    const int* __restrict__ tok, ushort* __restrict__ h) {
  const int NWG = 64 * 8 * NEXP;
  int flat = blockIdx.x;
  int wgid = (flat % 8) * (NWG / 8) + flat / 8;
  int m0 = (wgid & 63) * 128;
  int rest = wgid >> 6;
  int n0 = (rest & 7) * 256;
  int e = rest >> 3;
  int cnt = meta[e];
  if (m0 >= cnt) return;
  int bas = meta[16 + e];
  __shared__ char lds[73728];
  int tid = threadIdx.x;

  const char* w1e = (const char*)(w1t + (long)e * DFF * DMODEL);
  int rA = tid >> 2;
  int ch = tid & 3;
  auto sc = [&](int row) { return (unsigned)((ch * 16) ^ (((row >> 1) & 3) << 4)); };
  int ma0 = m0 + rA;        if (ma0 >= cnt) ma0 = cnt - 1;
  int ma1 = m0 + rA + 64;   if (ma1 >= cnt) ma1 = cnt - 1;
  const char* aP0 = (const char*)xb + (long)tok[bas + ma0] * (DMODEL * 2) + sc(rA);
  const char* aP1 = (const char*)xb + (long)tok[bas + ma1] * (DMODEL * 2) + sc(rA + 64);
  const char* bP0 = w1e + (long)(n0 + rA) * (DMODEL * 2) + sc(rA);
  const char* bP1 = w1e + (long)(n0 + rA + 64) * (DMODEL * 2) + sc(rA + 64);
  const char* bP2 = w1e + (long)(n0 + rA + 128) * (DMODEL * 2) + sc(rA + 128);
  const char* bP3 = w1e + (long)(n0 + rA + 192) * (DMODEL * 2) + sc(rA + 192);

  floatx4 acc[8][4];
#pragma unroll
  for (int i = 0; i < 8; ++i)
#pragma unroll
    for (int j = 0; j < 4; ++j) acc[i][j] = (floatx4){0.f, 0.f, 0.f, 0.f};

  gemm_pipe(DMODEL / 32, aP0, aP1, bP0, bP1, bP2, bP3, lds, tid, acc);

  int lane = tid & 63, wid = tid >> 6;
  int lr = lane & 15, lg = lane >> 4;
  const float* b1e = b1 + e * DFF;
#pragma unroll
  for (int mi = 0; mi < 8; ++mi) {
#pragma unroll
    for (int r = 0; r < 4; ++r) {
      int m = m0 + mi * 16 + lg * 4 + r;
      if (m >= cnt) continue;
      long hrow = (long)(bas + m) * DFF;
#pragma unroll
      for (int ni = 0; ni < 4; ++ni) {
        int f = n0 + wid * 64 + ni * 16 + lr;
        float v = acc[mi][ni][r] + b1e[f];
        h[hrow + f] = f2bf(fmaxf(v, 0.f));
      }
    }
  }
}

// ================= GEMM2: no-LDS direct-to-register (EXPERIMENT) =================
// Block 128x128 (4 waves, wave-tile 64x64, 2x2), zero LDS, zero barriers.
// Each lane loads its MFMA fragments straight from global (L1/L2-served):
// same (row, lg*16) mapping proven in the LDS path. Double-buffered frag regs,
// unroll 2; compiler emits counted vmcnt (m97/m131) and waves drift freely.
__global__ __launch_bounds__(256) void gemm2_kernel(
    const ushort* __restrict__ h, const ushort* __restrict__ w2t,
    const float* __restrict__ b2, const int* __restrict__ meta,
    const float* __restrict__ gate, ushort* __restrict__ y) {
  const int NWG = 64 * 8 * NEXP;  // m(64 tiles of 128) x n(8 of 128) x e
  int flat = blockIdx.x;
  int wgid = (flat % 8) * (NWG / 8) + flat / 8;  // bijective XCD swizzle
  int m0 = (wgid & 63) * 128;
  int rest = wgid >> 6;
  int n0 = (rest & 7) * 128;
  int e = rest >> 3;
  int cnt = meta[e];
  if (m0 >= cnt) return;
  int bas = meta[16 + e];
  int tid = threadIdx.x;
  int lane = tid & 63, wid = tid >> 6;
  int lr = lane & 15, lg = lane >> 4;
  int m0w = m0 + (wid >> 1) * 64;
  int n0w = n0 + (wid & 1) * 64;

  const char* w2e = (const char*)(w2t + (long)e * DMODEL * DFF);
  const char* aP[4];
  const char* bP[4];
#pragma unroll
  for (int mi = 0; mi < 4; ++mi) {
    int m = m0w + mi * 16 + lr; if (m >= cnt) m = cnt - 1;
    aP[mi] = (const char*)h + (long)(bas + m) * (DFF * 2) + lg * 16;
  }
#pragma unroll
  for (int ni = 0; ni < 4; ++ni) {
    int n = n0w + ni * 16 + lr;
    bP[ni] = w2e + (long)n * (DFF * 2) + lg * 16;
  }

  floatx4 acc[4][4];
#pragma unroll
  for (int i = 0; i < 4; ++i)
#pragma unroll
    for (int j = 0; j < 4; ++j) acc[i][j] = (floatx4){0.f, 0.f, 0.f, 0.f};

  const int NT = DFF / 32;  // 64
  short8v fA[2][4], fB[2][4];
#pragma unroll
  for (int i = 0; i < 4; ++i) {
    fA[0][i] = *(const short8v*)(aP[i]);
    fB[0][i] = *(const short8v*)(bP[i]);
  }
#pragma unroll 2
  for (int t = 0; t < NT - 1; ++t) {
    int cur = t & 1, nxt = cur ^ 1;
    long ko = (long)(t + 1) * 64;
#pragma unroll
    for (int i = 0; i < 4; ++i) {
      fA[nxt][i] = *(const short8v*)(aP[i] + ko);
      fB[nxt][i] = *(const short8v*)(bP[i] + ko);
    }
#pragma unroll
    for (int mi = 0; mi < 4; ++mi)
#pragma unroll
      for (int ni = 0; ni < 4; ++ni)
        acc[mi][ni] = __builtin_amdgcn_mfma_f32_16x16x32_bf16(
            fA[cur][mi], fB[cur][ni], acc[mi][ni], 0, 0, 0);
  }
  {
    int cur = (NT - 1) & 1;
#pragma unroll
    for (int mi = 0; mi < 4; ++mi)
#pragma unroll
      for (int ni = 0; ni < 4; ++ni)
        acc[mi][ni] = __builtin_amdgcn_mfma_f32_16x16x32_bf16(
            fA[cur][mi], fB[cur][ni], acc[mi][ni], 0, 0, 0);
  }

  const float* b2e = b2 + e * DMODEL;
#pragma unroll
  for (int mi = 0; mi < 4; ++mi) {
#pragma unroll
    for (int r = 0; r < 4; ++r) {
      int m = m0w + mi * 16 + lg * 4 + r;
      if (m >= cnt) continue;
      int slot = bas + m;
      float g = gate[slot];
      ushort* yr = y + (long)slot * DMODEL;
#pragma unroll
      for (int ni = 0; ni < 4; ++ni) {
        int n = n0w + ni * 16 + lr;
        float v = g * (acc[mi][ni][r] + b2e[n]);
        yr[n] = f2bf(v);
      }
    }
  }
}

// ---------------- combine: out[t] = y[slot1] + y[slot2]; entropy copy ----------------
__global__ __launch_bounds__(256) void combine_kernel(
    const ushort* __restrict__ y, const int* __restrict__ slotOf,
    const float* __restrict__ entWs, float* __restrict__ out) {
  int t = blockIdx.x;
  int s1 = slotOf[2 * t], s2 = slotOf[2 * t + 1];
  int d = threadIdx.x * 4;
  ushort4v a = *(const ushort4v*)&y[(long)s1 * DMODEL + d];
  ushort4v b = *(const ushort4v*)&y[(long)s2 * DMODEL + d];
  float4 r;
  r.x = bf2f(a[0]) + bf2f(b[0]);
  r.y = bf2f(a[1]) + bf2f(b[1]);
  r.z = bf2f(a[2]) + bf2f(b[2]);
  r.w = bf2f(a[3]) + bf2f(b[3]);
  *(float4*)&out[(long)t * DMODEL + d] = r;
  if (t == 0 && threadIdx.x == 0) out[(long)T_TOK * DMODEL] = *entWs;
}

extern "C" void kernel_launch(void* const* d_in, const int* in_sizes, int n_in,
                              void* d_out, int out_size, void* d_ws, size_t ws_size,
                              hipStream_t stream) {
  const float* x  = (const float*)d_in[0];
  const float* Wg = (const float*)d_in[1];
  const float* bg = (const float*)d_in[2];
  const float* W1 = (const float*)d_in[3];
  const float* b1 = (const float*)d_in[4];
  const float* W2 = (const float*)d_in[5];
  const float* b2 = (const float*)d_in[6];
  float* out = (float*)d_out;

  char* ws = (char*)d_ws;
  int*    meta   = (int*)(ws + 0);
  float*  entWs  = (float*)(ws + 256);
  int*    te     = (int*)(ws + 1024);
  float*  tg     = (float*)(ws + 66560);
  int*    tokA   = (int*)(ws + 132096);
  float*  gate   = (float*)(ws + 197632);
  int*    slotOf = (int*)(ws + 263168);
  ushort* xb     = (ushort*)(ws + 328704);    // 16 MB
  ushort* w1t    = (ushort*)(ws + 17105920);  // 32 MB (dead after gemm1 -> reused as y)
  ushort* w2t    = (ushort*)(ws + 50660352);  // 32 MB
  ushort* h      = (ushort*)(ws + 84214784);  // 64 MB
  ushort* y      = w1t;

  // tcvt2 first: block 0 zeroes meta/entWs (stream order covers gating's needs)
  tcvt2_kernel<<<8192, 256, 0, stream>>>(W1, W2, w1t, w2t, meta, entWs);
  gating_kernel<<<T_TOK / 8, 256, 0, stream>>>(x, Wg, bg, meta, te, tg, entWs, xb);
  prefix_kernel<<<1, 1, 0, stream>>>(meta);
  scatter_kernel<<<T_TOK / 256, 256, 0, stream>>>(te, tg, meta, tokA, gate, slotOf);
  gemm1_kernel<<<64 * 8 * NEXP, 256, 0, stream>>>(xb, w1t, b1, meta, tokA, h);
  gemm2_kernel<<<64 * 8 * NEXP, 256, 0, stream>>>(h, w2t, b2, meta, gate, y);
  combine_kernel<<<T_TOK, 256, 0, stream>>>(y, slotOf, entWs, out);
}

// Round 13
// 332.790 us; speedup vs baseline: 1.9531x; 1.9531x over previous
//
#include <hip/hip_runtime.h>
#include <hip/hip_bf16.h>

#define T_TOK 8192
#define DMODEL 1024
#define DFF 2048
#define NEXP 8

typedef __attribute__((ext_vector_type(8))) short short8v;
typedef __attribute__((ext_vector_type(4))) float floatx4;
typedef __attribute__((ext_vector_type(4))) ushort ushort4v;

__device__ __forceinline__ ushort f2bf(float f) {
  union { float f; unsigned u; } v; v.f = f;
  unsigned u = v.u;
  unsigned r = (u + 0x7FFFu + ((u >> 16) & 1u)) >> 16;
  return (ushort)r;
}
__device__ __forceinline__ float bf2f(ushort b) {
  union { unsigned u; float f; } v; v.u = ((unsigned)b) << 16;
  return v.f;
}
__device__ __forceinline__ void gload16(const void* g, void* l) {
  __builtin_amdgcn_global_load_lds(
      (const __attribute__((address_space(1))) unsigned int*)g,
      (__attribute__((address_space(3))) unsigned int*)l, 16, 0, 0);
}
__device__ __forceinline__ short8v dsr128(unsigned off) {
  short8v r;
  asm volatile("ds_read_b128 %0, %1" : "=v"(r) : "v"(off));
  return r;
}
#define VMW(n) asm volatile("s_waitcnt vmcnt(" #n ")" ::: "memory")
#define LG0()  asm volatile("s_waitcnt lgkmcnt(0)" ::: "memory")
#define BAR()  asm volatile("s_barrier" ::: "memory")
#define SB0()  __builtin_amdgcn_sched_barrier(0)

// ---------------- gating: 16 tokens/block, conflict-free Wg LDS, fused x->bf16 ----------------
// norm-modulation in the reference is a per-token uniform shift across experts:
// invariant for top-k indices and softmax(topv) -> skipped entirely.
// Wg LDS layout: addr(d,e) = 8d + e + (d>>2) (monotone pad -> injective).
__global__ __launch_bounds__(256) void gating_kernel(
    const float* __restrict__ x, const float* __restrict__ Wg,
    const float* __restrict__ bg, int* __restrict__ meta,
    int* __restrict__ te, float* __restrict__ tg, float* __restrict__ entWs,
    ushort* __restrict__ xb) {
  __shared__ float wgT[8448];
  __shared__ float sbg[NEXP];
  __shared__ int cnt_s[NEXP];
  __shared__ float ent_s;
  int tid = threadIdx.x;
#pragma unroll
  for (int k = 0; k < 8; ++k) {
    int g4 = tid + 256 * k;
    float4 v = ((const float4*)Wg)[g4];
    int q = g4 * 4;
    int f = q >> 5;
    wgT[q + f]     = v.x;
    wgT[q + 1 + f] = v.y;
    wgT[q + 2 + f] = v.z;
    wgT[q + 3 + f] = v.w;
  }
  if (tid < NEXP) { sbg[tid] = bg[tid]; cnt_s[tid] = 0; }
  if (tid == 0) ent_s = 0.f;
  __syncthreads();

  int wid = tid >> 6, lane = tid & 63;
#pragma unroll 1
  for (int it = 0; it < 4; ++it) {
    int t = blockIdx.x * 16 + wid * 4 + it;
    const float* xr = x + (long)t * DMODEL;
    ushort* xbr = xb + (long)t * DMODEL;
    float acc[NEXP];
#pragma unroll
    for (int e = 0; e < NEXP; ++e) acc[e] = 0.f;
#pragma unroll
    for (int i = 0; i < 4; ++i) {
      int dbase = i * 256 + lane * 4;
      int pad = i * 64 + lane;
      float4 xv = *(const float4*)(xr + dbase);
      ushort4v s;
      s[0] = f2bf(xv.x); s[1] = f2bf(xv.y); s[2] = f2bf(xv.z); s[3] = f2bf(xv.w);
      *(ushort4v*)(xbr + dbase) = s;
      float xj[4] = {xv.x, xv.y, xv.z, xv.w};
#pragma unroll
      for (int j = 0; j < 4; ++j) {
        int base = 8 * (dbase + j) + pad;
#pragma unroll
        for (int e = 0; e < NEXP; ++e) acc[e] += xj[j] * wgT[base + e];
      }
    }
#pragma unroll
    for (int off = 32; off; off >>= 1)
#pragma unroll
      for (int e = 0; e < NEXP; ++e) acc[e] += __shfl_xor(acc[e], off, 64);
    if (lane == 0) {
      float lg[NEXP];
#pragma unroll
      for (int e = 0; e < NEXP; ++e) lg[e] = acc[e] + sbg[e];
      int e1 = 0; float v1 = lg[0];
#pragma unroll
      for (int e = 1; e < NEXP; ++e) if (lg[e] > v1) { v1 = lg[e]; e1 = e; }
      int e2 = -1; float v2 = -1e30f;
#pragma unroll
      for (int e = 0; e < NEXP; ++e) if (e != e1 && lg[e] > v2) { v2 = lg[e]; e2 = e; }
      float p2 = expf(v2 - v1);
      float s = 1.f + p2;
      float g1 = 1.f / s, g2 = p2 / s;
      float ent = -(g1 * logf(fmaxf(g1, 1e-8f)) + g2 * logf(fmaxf(g2, 1e-8f)));
      atomicAdd(&cnt_s[e1], 1);
      atomicAdd(&cnt_s[e2], 1);
      atomicAdd(&ent_s, ent);
      te[2 * t] = e1; te[2 * t + 1] = e2;
      tg[2 * t] = g1; tg[2 * t + 1] = g2;
    }
  }
  __syncthreads();
  if (tid < NEXP && cnt_s[tid]) atomicAdd(&meta[tid], cnt_s[tid]);
  if (tid == 0) atomicAdd(entWs, ent_s * (1.f / T_TOK));
}

// meta layout (ints): counts @0..7, base @16..23, cursor @32..39
__global__ void prefix_kernel(int* __restrict__ meta) {
  if (threadIdx.x == 0) {
    int s = 0;
    for (int e = 0; e < NEXP; ++e) { meta[16 + e] = s; s += meta[e]; meta[32 + e] = 0; }
  }
}

__global__ void scatter_kernel(const int* __restrict__ te, const float* __restrict__ tg,
                               int* __restrict__ meta, int* __restrict__ tok,
                               float* __restrict__ gate, int* __restrict__ slotOf) {
  int t = blockIdx.x * blockDim.x + threadIdx.x;
  if (t >= T_TOK) return;
  for (int k = 0; k < 2; ++k) {
    int e = te[2 * t + k];
    int pos = atomicAdd(&meta[32 + e], 1);
    int slot = meta[16 + e] + pos;
    tok[slot] = t;
    gate[slot] = tg[2 * t + k];
    slotOf[2 * t + k] = slot;
  }
}

// ---------------- transpose+convert both weights; block 0 also does init ----------------
// Launched FIRST (stream order guarantees meta/entWs zeroed before gating runs).
// src[e][R][C] f32 -> dst[e][C][R] bf16.  id<4096: W1 (R=1024,C=2048); else W2.
__global__ __launch_bounds__(256) void tcvt2_kernel(
    const float* __restrict__ W1, const float* __restrict__ W2,
    ushort* __restrict__ w1t, ushort* __restrict__ w2t,
    int* __restrict__ meta, float* __restrict__ entWs) {
  int id = blockIdx.x;
  if (id == 0) {
    if (threadIdx.x < 64) meta[threadIdx.x] = 0;
    if (threadIdx.x == 64) *entWs = 0.f;
  }
  const float* src; ushort* dst; int R, C, r0, c0, e;
  if (id < 4096) {
    src = W1; dst = w1t; R = DMODEL; C = DFF;
    c0 = (id & 31) * 64; r0 = ((id >> 5) & 15) * 64; e = id >> 9;
  } else {
    int j = id - 4096;
    src = W2; dst = w2t; R = DFF; C = DMODEL;
    c0 = (j & 15) * 64; r0 = ((j >> 4) & 31) * 64; e = j >> 9;
  }
  __shared__ ushort tile[64][72];
  int tid = threadIdx.x;
  long eoff = (long)e * R * C;
  int lr = tid >> 4, lc = (tid & 15) * 4;
#pragma unroll
  for (int p = 0; p < 4; ++p) {
    int r = lr + p * 16;
    float4 v = *(const float4*)&src[eoff + (long)(r0 + r) * C + (c0 + lc)];
    tile[r][lc + 0] = f2bf(v.x); tile[r][lc + 1] = f2bf(v.y);
    tile[r][lc + 2] = f2bf(v.z); tile[r][lc + 3] = f2bf(v.w);
  }
  __syncthreads();
  int sr = tid >> 3, sc = (tid & 7) * 8;
#pragma unroll
  for (int p = 0; p < 2; ++p) {
    int c = sr + p * 32;
    short8v v;
#pragma unroll
    for (int j = 0; j < 8; ++j) v[j] = (short)tile[sc + j][c];
    *(short8v*)&dst[eoff + (long)(c0 + c) * R + (r0 + sc)] = v;
  }
}

// ================= pipelined grouped GEMM core (r7, proven best) =================
// Block tile 128(M)x256(N), BK=32; wave tile 128x64 (1Mx4N), acc[8][4].
// LDS: A [3][128][32] bf16 = 24 KB @0, B [3][256][32] = 48 KB @24576 -> 72 KB.
// K-slice staging units -> phase read order matches stage retirement order.
// XOR-swizzle ((row>>1)&3)<<4 within the 64B row (conflict-free, measured 0).
// Per tile: {12 ds_reads (staged 2 tiles ahead, pre-barrier) ; STG(t+2) ;
// VMW(6)=tile t+1's loads in flight ; BAR ; LG0 ; 32-MFMA burst ; BAR}.
// WAR ledger: STG targets (t+2)%3=(t-1)%3, whose readers all drained LG0
// before the trailing BAR of tile t-1 that every wave passed.
__device__ __forceinline__ void gemm_pipe(
    int NT, const char* aP0, const char* aP1,
    const char* bP0, const char* bP1, const char* bP2, const char* bP3,
    char* lds, int tid, floatx4 (&acc)[8][4]) {
  const unsigned ldsU = (unsigned)(unsigned long)lds;
  int lane = tid & 63, wid = tid >> 6;
  int lr = lane & 15, lg = lane >> 4;
  unsigned offA[8], offB[4];
#pragma unroll
  for (int mi = 0; mi < 8; ++mi) {
    int row = mi * 16 + lr;
    offA[mi] = row * 64 + ((lg * 16) ^ (((row >> 1) & 3) << 4));
  }
#pragma unroll
  for (int ni = 0; ni < 4; ++ni) {
    int row = wid * 64 + ni * 16 + lr;
    offB[ni] = row * 64 + ((lg * 16) ^ (((row >> 1) & 3) << 4));
  }

  auto STG = [&](int b, int t) {
    int koff = t * 64;
    char* da = lds + b * 8192;
    gload16(aP0 + koff, da + tid * 16);
    gload16(aP1 + koff, da + 4096 + tid * 16);
    char* db = lds + 24576 + b * 16384;
    gload16(bP0 + koff, db + tid * 16);
    gload16(bP1 + koff, db + 4096 + tid * 16);
    gload16(bP2 + koff, db + 8192 + tid * 16);
    gload16(bP3 + koff, db + 12288 + tid * 16);
  };
  auto RD = [&](int b, short8v (&af)[8], short8v (&bf)[4]) {
#pragma unroll
    for (int ni = 0; ni < 4; ++ni) bf[ni] = dsr128(ldsU + 24576u + (unsigned)(b * 16384) + offB[ni]);
#pragma unroll
    for (int mi = 0; mi < 8; ++mi) af[mi] = dsr128(ldsU + (unsigned)(b * 8192) + offA[mi]);
  };
  auto MM = [&](short8v (&af)[8], short8v (&bf)[4]) {
#pragma unroll
    for (int mi = 0; mi < 8; ++mi)
#pragma unroll
      for (int ni = 0; ni < 4; ++ni)
        acc[mi][ni] =
            __builtin_amdgcn_mfma_f32_16x16x32_bf16(af[mi], bf[ni], acc[mi][ni], 0, 0, 0);
  };

  // prologue: stage tiles 0 and 1; ensure tile 0 resident.
  STG(0, 0); STG(1, 1);
  VMW(6); BAR();

  short8v af[8], bf[4];
  int b = 0;
  for (int t = 0; t + 2 < NT; ++t) {
    RD(b, af, bf);                   // pre-barrier: data staged 2 tiles ahead
    int bs = (b == 0) ? 2 : b - 1;   // (t+2)%3 == buffer of tile t-1
    STG(bs, t + 2);
    VMW(6);                          // tile t+1's 6 loads complete
    BAR(); LG0(); SB0();
    __builtin_amdgcn_s_setprio(1); MM(af, bf); __builtin_amdgcn_s_setprio(0);
    SB0(); BAR();
    b = (b == 2) ? 0 : b + 1;
  }
  { // tile NT-2: no stage; VMW(0) drains tile NT-1's loads
    RD(b, af, bf);
    VMW(0);
    BAR(); LG0(); SB0();
    __builtin_amdgcn_s_setprio(1); MM(af, bf); __builtin_amdgcn_s_setprio(0);
    SB0(); BAR();
    b = (b == 2) ? 0 : b + 1;
  }
  { // tile NT-1: nothing outstanding
    RD(b, af, bf);
    LG0(); SB0();
    __builtin_amdgcn_s_setprio(1); MM(af, bf); __builtin_amdgcn_s_setprio(0);
  }
}

// ---------------- GEMM1: h = relu(x[tok] @ W1 + b1) ----------------
__global__ __launch_bounds__(256, 2) void gemm1_kernel(
    const ushort* __restrict__ xb, const ushort* __restrict__ w1t,
    const float* __restrict__ b1, const int* __restrict__ meta,
    const int* __restrict__ tok, ushort* __restrict__ h) {
  const int NWG = 64 * 8 * NEXP;  // mtiles(64) x ntiles(8) x experts
  int flat = blockIdx.x;
  int wgid = (flat % 8) * (NWG / 8) + flat / 8;  // bijective XCD swizzle
  int m0 = (wgid & 63) * 128;
  int rest = wgid >> 6;
  int n0 = (rest & 7) * 256;
  int e = rest >> 3;
  int cnt = meta[e];
  if (m0 >= cnt) return;
  int bas = meta[16 + e];
  __shared__ char lds[73728];
  int tid = threadIdx.x;

  const char* w1e = (const char*)(w1t + (long)e * DFF * DMODEL);
  int rA = tid >> 2;
  int ch = tid & 3;
  auto sc = [&](int row) { return (unsigned)((ch * 16) ^ (((row >> 1) & 3) << 4)); };
  int ma0 = m0 + rA;        if (ma0 >= cnt) ma0 = cnt - 1;
  int ma1 = m0 + rA + 64;   if (ma1 >= cnt) ma1 = cnt - 1;
  const char* aP0 = (const char*)xb + (long)tok[bas + ma0] * (DMODEL * 2) + sc(rA);
  const char* aP1 = (const char*)xb + (long)tok[bas + ma1] * (DMODEL * 2) + sc(rA + 64);
  const char* bP0 = w1e + (long)(n0 + rA) * (DMODEL * 2) + sc(rA);
  const char* bP1 = w1e + (long)(n0 + rA + 64) * (DMODEL * 2) + sc(rA + 64);
  const char* bP2 = w1e + (long)(n0 + rA + 128) * (DMODEL * 2) + sc(rA + 128);
  const char* bP3 = w1e + (long)(n0 + rA + 192) * (DMODEL * 2) + sc(rA + 192);

  floatx4 acc[8][4];
#pragma unroll
  for (int i = 0; i < 8; ++i)
#pragma unroll
    for (int j = 0; j < 4; ++j) acc[i][j] = (floatx4){0.f, 0.f, 0.f, 0.f};

  gemm_pipe(DMODEL / 32, aP0, aP1, bP0, bP1, bP2, bP3, lds, tid, acc);

  int lane = tid & 63, wid = tid >> 6;
  int lr = lane & 15, lg = lane >> 4;
  const float* b1e = b1 + e * DFF;
#pragma unroll
  for (int mi = 0; mi < 8; ++mi) {
#pragma unroll
    for (int r = 0; r < 4; ++r) {
      int m = m0 + mi * 16 + lg * 4 + r;
      if (m >= cnt) continue;
      long hrow = (long)(bas + m) * DFF;
#pragma unroll
      for (int ni = 0; ni < 4; ++ni) {
        int f = n0 + wid * 64 + ni * 16 + lr;
        float v = acc[mi][ni][r] + b1e[f];
        h[hrow + f] = f2bf(fmaxf(v, 0.f));
      }
    }
  }
}

// ---------------- GEMM2: y[slot] = gate * (h[slot] @ W2 + b2) ----------------
__global__ __launch_bounds__(256, 2) void gemm2_kernel(
    const ushort* __restrict__ h, const ushort* __restrict__ w2t,
    const float* __restrict__ b2, const int* __restrict__ meta,
    const float* __restrict__ gate, ushort* __restrict__ y) {
  const int NWG = 64 * 4 * NEXP;
  int flat = blockIdx.x;
  int wgid = (flat % 8) * (NWG / 8) + flat / 8;
  int m0 = (wgid & 63) * 128;
  int rest = wgid >> 6;
  int n0 = (rest & 3) * 256;
  int e = rest >> 2;
  int cnt = meta[e];
  if (m0 >= cnt) return;
  int bas = meta[16 + e];
  __shared__ char lds[73728];
  int tid = threadIdx.x;

  const char* w2e = (const char*)(w2t + (long)e * DMODEL * DFF);
  int rA = tid >> 2;
  int ch = tid & 3;
  auto sc = [&](int row) { return (unsigned)((ch * 16) ^ (((row >> 1) & 3) << 4)); };
  int ma0 = m0 + rA;        if (ma0 >= cnt) ma0 = cnt - 1;
  int ma1 = m0 + rA + 64;   if (ma1 >= cnt) ma1 = cnt - 1;
  const char* aP0 = (const char*)h + (long)(bas + ma0) * (DFF * 2) + sc(rA);
  const char* aP1 = (const char*)h + (long)(bas + ma1) * (DFF * 2) + sc(rA + 64);
  const char* bP0 = w2e + (long)(n0 + rA) * (DFF * 2) + sc(rA);
  const char* bP1 = w2e + (long)(n0 + rA + 64) * (DFF * 2) + sc(rA + 64);
  const char* bP2 = w2e + (long)(n0 + rA + 128) * (DFF * 2) + sc(rA + 128);
  const char* bP3 = w2e + (long)(n0 + rA + 192) * (DFF * 2) + sc(rA + 192);

  floatx4 acc[8][4];
#pragma unroll
  for (int i = 0; i < 8; ++i)
#pragma unroll
    for (int j = 0; j < 4; ++j) acc[i][j] = (floatx4){0.f, 0.f, 0.f, 0.f};

  gemm_pipe(DFF / 32, aP0, aP1, bP0, bP1, bP2, bP3, lds, tid, acc);

  int lane = tid & 63, wid = tid >> 6;
  int lr = lane & 15, lg = lane >> 4;
  const float* b2e = b2 + e * DMODEL;
#pragma unroll
  for (int mi = 0; mi < 8; ++mi) {
#pragma unroll
    for (int r = 0; r < 4; ++r) {
      int m = m0 + mi * 16 + lg * 4 + r;
      if (m >= cnt) continue;
      int slot = bas + m;
      float g = gate[slot];
      ushort* yr = y + (long)slot * DMODEL;
#pragma unroll
      for (int ni = 0; ni < 4; ++ni) {
        int n = n0 + wid * 64 + ni * 16 + lr;
        float v = g * (acc[mi][ni][r] + b2e[n]);
        yr[n] = f2bf(v);
      }
    }
  }
}

// ---------------- combine: out[t] = y[slot1] + y[slot2]; entropy copy ----------------
__global__ __launch_bounds__(256) void combine_kernel(
    const ushort* __restrict__ y, const int* __restrict__ slotOf,
    const float* __restrict__ entWs, float* __restrict__ out) {
  int t = blockIdx.x;
  int s1 = slotOf[2 * t], s2 = slotOf[2 * t + 1];
  int d = threadIdx.x * 4;
  ushort4v a = *(const ushort4v*)&y[(long)s1 * DMODEL + d];
  ushort4v b = *(const ushort4v*)&y[(long)s2 * DMODEL + d];
  float4 r;
  r.x = bf2f(a[0]) + bf2f(b[0]);
  r.y = bf2f(a[1]) + bf2f(b[1]);
  r.z = bf2f(a[2]) + bf2f(b[2]);
  r.w = bf2f(a[3]) + bf2f(b[3]);
  *(float4*)&out[(long)t * DMODEL + d] = r;
  if (t == 0 && threadIdx.x == 0) out[(long)T_TOK * DMODEL] = *entWs;
}

extern "C" void kernel_launch(void* const* d_in, const int* in_sizes, int n_in,
                              void* d_out, int out_size, void* d_ws, size_t ws_size,
                              hipStream_t stream) {
  const float* x  = (const float*)d_in[0];
  const float* Wg = (const float*)d_in[1];
  const float* bg = (const float*)d_in[2];
  const float* W1 = (const float*)d_in[3];
  const float* b1 = (const float*)d_in[4];
  const float* W2 = (const float*)d_in[5];
  const float* b2 = (const float*)d_in[6];
  float* out = (float*)d_out;

  char* ws = (char*)d_ws;
  int*    meta   = (int*)(ws + 0);
  float*  entWs  = (float*)(ws + 256);
  int*    te     = (int*)(ws + 1024);
  float*  tg     = (float*)(ws + 66560);
  int*    tokA   = (int*)(ws + 132096);
  float*  gate   = (float*)(ws + 197632);
  int*    slotOf = (int*)(ws + 263168);
  ushort* xb     = (ushort*)(ws + 328704);    // 16 MB
  ushort* w1t    = (ushort*)(ws + 17105920);  // 32 MB (dead after gemm1 -> reused as y)
  ushort* w2t    = (ushort*)(ws + 50660352);  // 32 MB
  ushort* h      = (ushort*)(ws + 84214784);  // 64 MB
  ushort* y      = w1t;

  // tcvt2 first: block 0 zeroes meta/entWs (stream order covers gating's needs)
  tcvt2_kernel<<<8192, 256, 0, stream>>>(W1, W2, w1t, w2t, meta, entWs);
  gating_kernel<<<T_TOK / 16, 256, 0, stream>>>(x, Wg, bg, meta, te, tg, entWs, xb);
  prefix_kernel<<<1, 1, 0, stream>>>(meta);
  scatter_kernel<<<T_TOK / 256, 256, 0, stream>>>(te, tg, meta, tokA, gate, slotOf);
  gemm1_kernel<<<64 * 8 * NEXP, 256, 0, stream>>>(xb, w1t, b1, meta, tokA, h);
  gemm2_kernel<<<64 * 4 * NEXP, 256, 0, stream>>>(h, w2t, b2, meta, gate, y);
  combine_kernel<<<T_TOK, 256, 0, stream>>>(y, slotOf, entWs, out);
}